// Round 1
// baseline (37.416 us; speedup 1.0000x reference)
//
#include <hip/hip_runtime.h>

#define MAX_N 20

__global__ void __launch_bounds__(256) plu_kernel(
    const float* __restrict__ x,
    const float* __restrict__ Nptr,
    const float* __restrict__ Bounds,
    const float* __restrict__ BoundSlope,
    const float* __restrict__ nheight,
    float* __restrict__ out,
    int n4,   // number of float4 packets
    int n)    // total elements
{
    __shared__ float sY[MAX_N + 1];  // nheight table  (21 entries -> banks 0..20, conflict-free)
    __shared__ float sK[MAX_N];      // per-interval slope (Y1-Y0)/len (20 entries, conflict-free)

    // Uniform scalars (compiler emits s_load for these: uniform address, no lane dependence)
    const float Nv = Nptr[0];
    const float Bl = Bounds[0];
    const float Br = Bounds[1];
    const float Kl = BoundSlope[0];
    const float Kr = BoundSlope[1];
    const float intervals = floorf(fminf(fmaxf(Nv, 3.0f), (float)MAX_N));
    const float interval_length = (Br - Bl) / intervals;   // matches reference numerics

    if (threadIdx.x < MAX_N + 1) sY[threadIdx.x] = nheight[threadIdx.x];
    __syncthreads();
    if (threadIdx.x < MAX_N)
        sK[threadIdx.x] = (sY[threadIdx.x + 1] - sY[threadIdx.x]) / interval_length;
    __syncthreads();

    const float h0  = sY[0];
    const float top = sY[(int)(intervals + 1.0f)];

    const float4* __restrict__ x4 = reinterpret_cast<const float4*>(x);
    float4* __restrict__ o4 = reinterpret_cast<float4*>(out);

    const int stride = gridDim.x * blockDim.x;
    const int tid = blockIdx.x * blockDim.x + threadIdx.x;

    for (int i = tid; i < n4; i += stride) {
        float4 v = x4[i];
        float4 r;
        float* vp = reinterpret_cast<float*>(&v);
        float* rp = reinterpret_cast<float*>(&r);
        #pragma unroll
        for (int j = 0; j < 4; ++j) {
            const float xx = vp[j];
            // idx_f via true IEEE f32 division to match reference floor boundaries
            const float idx_f = floorf((xx - Bl) / interval_length);
            const float Bidx  = idx_f * interval_length + Bl;
            int idx = (int)idx_f;
            idx = idx < 0 ? 0 : (idx > MAX_N - 1 ? MAX_N - 1 : idx);
            const float Y0   = sY[idx];
            const float Kidx = sK[idx];

            // mutually exclusive, all-finite -> select chain == masked sum
            float res = (xx - Bidx) * Kidx + Y0;            // b3: Bl <= x < Br
            res = (xx <  Bl) ? ((xx - Bl) * Kl + h0)  : res; // b1
            res = (xx >= Br) ? ((xx - Br) * Kr + top) : res; // b2
            rp[j] = res;
        }
        o4[i] = r;
    }

    // scalar tail (n % 4 != 0 safety; n is divisible by 4 for this problem)
    for (int i = n4 * 4 + tid; i < n; i += stride) {
        const float xx = x[i];
        const float idx_f = floorf((xx - Bl) / interval_length);
        const float Bidx  = idx_f * interval_length + Bl;
        int idx = (int)idx_f;
        idx = idx < 0 ? 0 : (idx > MAX_N - 1 ? MAX_N - 1 : idx);
        const float Y0   = sY[idx];
        const float Kidx = sK[idx];
        float res = (xx - Bidx) * Kidx + Y0;
        res = (xx <  Bl) ? ((xx - Bl) * Kl + h0)  : res;
        res = (xx >= Br) ? ((xx - Br) * Kr + top) : res;
        out[i] = res;
    }
}

extern "C" void kernel_launch(void* const* d_in, const int* in_sizes, int n_in,
                              void* d_out, int out_size, void* d_ws, size_t ws_size,
                              hipStream_t stream) {
    const float* x          = (const float*)d_in[0];
    const float* N          = (const float*)d_in[1];
    const float* Bounds     = (const float*)d_in[2];
    const float* BoundSlope = (const float*)d_in[3];
    const float* nheight    = (const float*)d_in[4];
    float* out = (float*)d_out;

    const int n  = in_sizes[0];
    const int n4 = n / 4;

    const int block = 256;
    // 2048 blocks = 8 blocks/CU * 256 CU -> 32 waves/CU, grid-stride covers the rest
    int grid = (n4 + block - 1) / block;
    if (grid > 2048) grid = 2048;
    if (grid < 1) grid = 1;

    plu_kernel<<<grid, block, 0, stream>>>(x, N, Bounds, BoundSlope, nheight, out, n4, n);
}

// Round 3
// 36.924 us; speedup vs baseline: 1.0133x; 1.0133x over previous
//
#include <hip/hip_runtime.h>

#define MAX_N 20

typedef float vfloat4 __attribute__((ext_vector_type(4)));  // clang vector: valid for nontemporal builtins

__global__ void __launch_bounds__(256) plu_kernel(
    const float* __restrict__ x,
    const float* __restrict__ Nptr,
    const float* __restrict__ Bounds,
    const float* __restrict__ BoundSlope,
    const float* __restrict__ nheight,
    float* __restrict__ out,
    int n4,   // number of float4 packets
    int n)    // total elements
{
    // Packed table: sYD[k] = { Y[k], Y[k+1]-Y[k] } -> one ds_read_b64 per lookup.
    __shared__ float2 sYD[MAX_N];

    // Uniform scalars (single read per block; negligible traffic)
    const float Nv = Nptr[0];
    const float Bl = Bounds[0];
    const float Br = Bounds[1];
    const float Kl = BoundSlope[0];
    const float Kr = BoundSlope[1];
    const float intervals = floorf(fminf(fmaxf(Nv, 3.0f), (float)MAX_N));
    const float interval_length = (Br - Bl) / intervals;
    const float inv_len = 1.0f / interval_length;

    if (threadIdx.x < MAX_N) {
        const float y0 = nheight[threadIdx.x];
        const float y1 = nheight[threadIdx.x + 1];
        sYD[threadIdx.x] = make_float2(y0, y1 - y0);
    }
    __syncthreads();

    const float h0  = nheight[0];
    const float top = nheight[(int)(intervals + 1.0f)];
    // boundary lines as single fmas: l1 = x*Kl + (h0 - Bl*Kl), l2 = x*Kr + (top - Br*Kr)
    const float C1 = h0  - Bl * Kl;
    const float C2 = top - Br * Kr;

    const vfloat4* __restrict__ x4 = reinterpret_cast<const vfloat4*>(x);
    vfloat4* __restrict__ o4 = reinterpret_cast<vfloat4*>(out);

    const int stride = gridDim.x * blockDim.x;
    const int tid = blockIdx.x * blockDim.x + threadIdx.x;

    for (int i = tid; i < n4; i += stride) {
        vfloat4 v = x4[i];
        vfloat4 r;
        #pragma unroll
        for (int j = 0; j < 4; ++j) {
            const float xx = v[j];
            const float t  = (xx - Bl) * inv_len;          // == (x-Bl)/len within 1 ulp
            const float f  = floorf(t);
            const int idx  = (int)fminf(fmaxf(f, 0.0f), (float)(MAX_N - 1));
            const float2 yd = sYD[idx];                    // ds_read_b64
            // l3 = (x - Bidx)*Kidx + Y0 == (t - f)*(Y1-Y0) + Y0
            float res = fmaf(t - f, yd.y, yd.x);
            res = (xx <  Bl) ? fmaf(xx, Kl, C1) : res;     // b1
            res = (xx >= Br) ? fmaf(xx, Kr, C2) : res;     // b2
            r[j] = res;
        }
        __builtin_nontemporal_store(r, &o4[i]);            // nt store: keep L3 for x reads
    }

    // scalar tail (unused for this shape; kept for safety)
    for (int i = n4 * 4 + tid; i < n; i += stride) {
        const float xx = x[i];
        const float t  = (xx - Bl) * inv_len;
        const float f  = floorf(t);
        const int idx  = (int)fminf(fmaxf(f, 0.0f), (float)(MAX_N - 1));
        const float2 yd = sYD[idx];
        float res = fmaf(t - f, yd.y, yd.x);
        res = (xx <  Bl) ? fmaf(xx, Kl, C1) : res;
        res = (xx >= Br) ? fmaf(xx, Kr, C2) : res;
        __builtin_nontemporal_store(res, &out[i]);
    }
}

extern "C" void kernel_launch(void* const* d_in, const int* in_sizes, int n_in,
                              void* d_out, int out_size, void* d_ws, size_t ws_size,
                              hipStream_t stream) {
    const float* x          = (const float*)d_in[0];
    const float* N          = (const float*)d_in[1];
    const float* Bounds     = (const float*)d_in[2];
    const float* BoundSlope = (const float*)d_in[3];
    const float* nheight    = (const float*)d_in[4];
    float* out = (float*)d_out;

    const int n  = in_sizes[0];
    const int n4 = n / 4;

    const int block = 256;
    // 2048 blocks = 8 blocks/CU * 256 CU -> 32 waves/CU, grid-stride covers the rest
    int grid = (n4 + block - 1) / block;
    if (grid > 2048) grid = 2048;
    if (grid < 1) grid = 1;

    plu_kernel<<<grid, block, 0, stream>>>(x, N, Bounds, BoundSlope, nheight, out, n4, n);
}

// Round 4
// 36.836 us; speedup vs baseline: 1.0157x; 1.0024x over previous
//
#include <hip/hip_runtime.h>

#define MAX_N 20

typedef float vfloat4 __attribute__((ext_vector_type(4)));  // clang vector: valid for nontemporal builtins

__global__ void __launch_bounds__(256) plu_kernel(
    const float* __restrict__ x,
    const float* __restrict__ Nptr,
    const float* __restrict__ Bounds,
    const float* __restrict__ BoundSlope,
    const float* __restrict__ nheight,
    float* __restrict__ out,
    int n4,   // number of float4 packets
    int n)    // total elements
{
    // Packed table: sYD[k] = { Y[k], Y[k+1]-Y[k] } -> one ds_read_b64 per lookup.
    __shared__ float2 sYD[MAX_N];

    const float Nv = Nptr[0];
    const float Bl = Bounds[0];
    const float Br = Bounds[1];
    const float Kl = BoundSlope[0];
    const float Kr = BoundSlope[1];
    const float intervals = floorf(fminf(fmaxf(Nv, 3.0f), (float)MAX_N));
    const float interval_length = (Br - Bl) / intervals;
    const float inv_len = 1.0f / interval_length;

    if (threadIdx.x < MAX_N) {
        const float y0 = nheight[threadIdx.x];
        const float y1 = nheight[threadIdx.x + 1];
        sYD[threadIdx.x] = make_float2(y0, y1 - y0);
    }
    __syncthreads();

    const float h0  = nheight[0];
    const float top = nheight[(int)(intervals + 1.0f)];
    // boundary lines as single fmas: l1 = x*Kl + (h0 - Bl*Kl), l2 = x*Kr + (top - Br*Kr)
    const float C1 = h0  - Bl * Kl;
    const float C2 = top - Br * Kr;

    const vfloat4* __restrict__ x4 = reinterpret_cast<const vfloat4*>(x);
    vfloat4* __restrict__ o4 = reinterpret_cast<vfloat4*>(out);

    const int stride = gridDim.x * blockDim.x;
    const int tid = blockIdx.x * blockDim.x + threadIdx.x;

    auto piece = [&](float xx) -> float {
        const float t  = (xx - Bl) * inv_len;              // == (x-Bl)/len within 1 ulp
        const float f  = floorf(t);
        const int idx  = (int)fminf(fmaxf(f, 0.0f), (float)(MAX_N - 1));
        const float2 yd = sYD[idx];                        // ds_read_b64
        float res = fmaf(t - f, yd.y, yd.x);               // (t-f)*(Y1-Y0) + Y0
        res = (xx <  Bl) ? fmaf(xx, Kl, C1) : res;         // b1
        res = (xx >= Br) ? fmaf(xx, Kr, C2) : res;         // b2
        return res;
    };

    int i = tid;
    // 2x unroll: two independent 16B loads in flight per iteration (8 indep chains)
    for (; i + stride < n4; i += 2 * stride) {
        vfloat4 a = x4[i];
        vfloat4 b = x4[i + stride];
        vfloat4 ra, rb;
        #pragma unroll
        for (int j = 0; j < 4; ++j) ra[j] = piece(a[j]);
        #pragma unroll
        for (int j = 0; j < 4; ++j) rb[j] = piece(b[j]);
        __builtin_nontemporal_store(ra, &o4[i]);
        __builtin_nontemporal_store(rb, &o4[i + stride]);
    }
    if (i < n4) {
        vfloat4 a = x4[i];
        vfloat4 ra;
        #pragma unroll
        for (int j = 0; j < 4; ++j) ra[j] = piece(a[j]);
        __builtin_nontemporal_store(ra, &o4[i]);
    }

    // scalar tail (unused for this shape; kept for safety)
    for (int k = n4 * 4 + tid; k < n; k += stride) {
        __builtin_nontemporal_store(piece(x[k]), &out[k]);
    }
}

extern "C" void kernel_launch(void* const* d_in, const int* in_sizes, int n_in,
                              void* d_out, int out_size, void* d_ws, size_t ws_size,
                              hipStream_t stream) {
    const float* x          = (const float*)d_in[0];
    const float* N          = (const float*)d_in[1];
    const float* Bounds     = (const float*)d_in[2];
    const float* BoundSlope = (const float*)d_in[3];
    const float* nheight    = (const float*)d_in[4];
    float* out = (float*)d_out;

    const int n  = in_sizes[0];
    const int n4 = n / 4;

    const int block = 256;
    // 2048 blocks = 8 blocks/CU * 256 CU -> 32 waves/CU, grid-stride covers the rest
    int grid = (n4 + block - 1) / block;
    if (grid > 2048) grid = 2048;
    if (grid < 1) grid = 1;

    plu_kernel<<<grid, block, 0, stream>>>(x, N, Bounds, BoundSlope, nheight, out, n4, n);
}

// Round 5
// 35.555 us; speedup vs baseline: 1.0523x; 1.0360x over previous
//
#include <hip/hip_runtime.h>

#define MAX_N 20

typedef float vfloat4 __attribute__((ext_vector_type(4)));  // clang vector: valid for nontemporal builtins

__global__ void __launch_bounds__(256) plu_kernel(
    const float* __restrict__ x,
    const float* __restrict__ Nptr,
    const float* __restrict__ Bounds,
    const float* __restrict__ BoundSlope,
    const float* __restrict__ nheight,
    float* __restrict__ out,
    int n4,   // number of float4 packets
    int n)    // total elements
{
    // Packed table: sYD[k] = { Y[k], Y[k+1]-Y[k] } -> one ds_read_b64 per lookup.
    __shared__ float2 sYD[MAX_N];

    const float Nv = Nptr[0];
    const float Bl = Bounds[0];
    const float Br = Bounds[1];
    const float Kl = BoundSlope[0];
    const float Kr = BoundSlope[1];
    const float intervals = floorf(fminf(fmaxf(Nv, 3.0f), (float)MAX_N));
    const float interval_length = (Br - Bl) / intervals;
    const float inv_len = 1.0f / interval_length;

    if (threadIdx.x < MAX_N) {
        const float y0 = nheight[threadIdx.x];
        const float y1 = nheight[threadIdx.x + 1];
        sYD[threadIdx.x] = make_float2(y0, y1 - y0);
    }
    __syncthreads();

    const float h0  = nheight[0];
    const float top = nheight[(int)(intervals + 1.0f)];
    // boundary lines as single fmas: l1 = x*Kl + (h0 - Bl*Kl), l2 = x*Kr + (top - Br*Kr)
    const float C1 = h0  - Bl * Kl;
    const float C2 = top - Br * Kr;

    const vfloat4* __restrict__ x4 = reinterpret_cast<const vfloat4*>(x);
    vfloat4* __restrict__ o4 = reinterpret_cast<vfloat4*>(out);

    auto piece = [&](float xx) -> float {
        const float t  = (xx - Bl) * inv_len;              // == (x-Bl)/len within 1 ulp
        const float f  = floorf(t);
        const int idx  = (int)fminf(fmaxf(f, 0.0f), (float)(MAX_N - 1));
        const float2 yd = sYD[idx];                        // ds_read_b64, conflict-free
        float res = fmaf(t - f, yd.y, yd.x);               // (t-f)*(Y1-Y0) + Y0
        res = (xx <  Bl) ? fmaf(xx, Kl, C1) : res;         // b1
        res = (xx >= Br) ? fmaf(xx, Kr, C2) : res;         // b2
        return res;
    };

    // Flat grid: one float4 packet per thread. Max TLP, no loop overhead.
    const int i = blockIdx.x * blockDim.x + threadIdx.x;
    if (i < n4) {
        vfloat4 v = x4[i];
        vfloat4 r;
        #pragma unroll
        for (int j = 0; j < 4; ++j) r[j] = piece(v[j]);
        __builtin_nontemporal_store(r, &o4[i]);            // nt store: keep L3 for x reads
    }

    // scalar tail (n % 4 != 0 safety; unused for this shape)
    const int k = n4 * 4 + i;
    if (k < n) {
        __builtin_nontemporal_store(piece(x[k]), &out[k]);
    }
}

extern "C" void kernel_launch(void* const* d_in, const int* in_sizes, int n_in,
                              void* d_out, int out_size, void* d_ws, size_t ws_size,
                              hipStream_t stream) {
    const float* x          = (const float*)d_in[0];
    const float* N          = (const float*)d_in[1];
    const float* Bounds     = (const float*)d_in[2];
    const float* BoundSlope = (const float*)d_in[3];
    const float* nheight    = (const float*)d_in[4];
    float* out = (float*)d_out;

    const int n  = in_sizes[0];
    const int n4 = n / 4;

    const int block = 256;
    int grid = (n4 + block - 1) / block;   // full flat grid: 25088 blocks for this shape
    if (grid < 1) grid = 1;

    plu_kernel<<<grid, block, 0, stream>>>(x, N, Bounds, BoundSlope, nheight, out, n4, n);
}

// Round 6
// 35.080 us; speedup vs baseline: 1.0666x; 1.0135x over previous
//
#include <hip/hip_runtime.h>

#define MAX_N 20

typedef float vfloat4 __attribute__((ext_vector_type(4)));

__global__ void __launch_bounds__(256) plu_kernel(
    const float* __restrict__ x,
    const float* __restrict__ Nptr,
    const float* __restrict__ Bounds,
    const float* __restrict__ BoundSlope,
    const float* __restrict__ nheight,
    float* __restrict__ out,
    int n4,   // number of float4 packets
    int n)    // total elements
{
    // Packed table: sYD[k] = { Y[k], Y[k+1]-Y[k] } -> one ds_read_b64 per lookup.
    __shared__ float2 sYD[MAX_N];

    const float Nv = Nptr[0];
    const float Bl = Bounds[0];
    const float Br = Bounds[1];
    const float Kl = BoundSlope[0];
    const float Kr = BoundSlope[1];
    const float intervals = floorf(fminf(fmaxf(Nv, 3.0f), (float)MAX_N));
    const float interval_length = (Br - Bl) / intervals;
    const float inv_len = 1.0f / interval_length;

    if (threadIdx.x < MAX_N) {
        const float y0 = nheight[threadIdx.x];
        const float y1 = nheight[threadIdx.x + 1];
        sYD[threadIdx.x] = make_float2(y0, y1 - y0);
    }
    __syncthreads();

    const float h0  = nheight[0];
    const float top = nheight[(int)(intervals + 1.0f)];
    // boundary lines as single fmas: l1 = x*Kl + (h0 - Bl*Kl), l2 = x*Kr + (top - Br*Kr)
    const float C1 = h0  - Bl * Kl;
    const float C2 = top - Br * Kr;

    const vfloat4* __restrict__ x4 = reinterpret_cast<const vfloat4*>(x);
    vfloat4* __restrict__ o4 = reinterpret_cast<vfloat4*>(out);

    auto piece = [&](float xx) -> float {
        const float t  = (xx - Bl) * inv_len;              // == (x-Bl)/len within 1 ulp
        const float f  = floorf(t);
        const int idx  = (int)fminf(fmaxf(f, 0.0f), (float)(MAX_N - 1));
        const float2 yd = sYD[idx];                        // ds_read_b64, conflict-free
        float res = fmaf(t - f, yd.y, yd.x);               // (t-f)*(Y1-Y0) + Y0
        res = (xx <  Bl) ? fmaf(xx, Kl, C1) : res;         // b1
        res = (xx >= Br) ? fmaf(xx, Kr, C2) : res;         // b2
        return res;
    };

    // Flat grid: one float4 packet per thread. Max TLP, no loop overhead.
    const int i = blockIdx.x * blockDim.x + threadIdx.x;
    if (i < n4) {
        vfloat4 v = x4[i];
        vfloat4 r;
        #pragma unroll
        for (int j = 0; j < 4; ++j) r[j] = piece(v[j]);
        o4[i] = r;                                         // A/B: plain temporal store (vs round-5 nt)
    }

    // scalar tail (n % 4 != 0 safety; unused for this shape)
    const int k = n4 * 4 + i;
    if (k < n) {
        out[k] = piece(x[k]);
    }
}

extern "C" void kernel_launch(void* const* d_in, const int* in_sizes, int n_in,
                              void* d_out, int out_size, void* d_ws, size_t ws_size,
                              hipStream_t stream) {
    const float* x          = (const float*)d_in[0];
    const float* N          = (const float*)d_in[1];
    const float* Bounds     = (const float*)d_in[2];
    const float* BoundSlope = (const float*)d_in[3];
    const float* nheight    = (const float*)d_in[4];
    float* out = (float*)d_out;

    const int n  = in_sizes[0];
    const int n4 = n / 4;

    const int block = 256;
    int grid = (n4 + block - 1) / block;   // full flat grid: 25088 blocks for this shape
    if (grid < 1) grid = 1;

    plu_kernel<<<grid, block, 0, stream>>>(x, N, Bounds, BoundSlope, nheight, out, n4, n);
}